// Round 10
// baseline (81.322 us; speedup 1.0000x reference)
//
#include <hip/hip_runtime.h>
#include <stdint.h>

#define NN 8192
#define DD 512
#define BM 128
#define BK2 32            // bf16 elements per K-step (dbuf) = 64 B rows in LDS
#define NKT2 (DD / BK2)   // 16 K-steps
#define NB 64             // NN / BM
#define NTILES 2080       // NB*(NB+1)/2 upper-triangular tiles

typedef short s16x8 __attribute__((ext_vector_type(8)));
typedef float f32x4 __attribute__((ext_vector_type(4)));

static __device__ __forceinline__ short f2bf(float x) {
  union { float f; uint32_t u; } c; c.f = x;
  uint32_t r = c.u + 0x7fffu + ((c.u >> 16) & 1u);   // RNE
  return (short)(r >> 16);
}

static __device__ __forceinline__ int tri_off(int b) {
  return b * NB - (b * (b - 1)) / 2;
}

static __device__ __forceinline__ void gload16(const void* g, void* l) {
  __builtin_amdgcn_global_load_lds(
      (const __attribute__((address_space(1))) void*)g,
      (__attribute__((address_space(3))) void*)l, 16, 0, 0);
}

// 4 waves/block, one row per wave: fp32 -> bf16, sq-norm, init reductions.
__global__ __launch_bounds__(256) void prep_kernel(
    const float* __restrict__ f, short* __restrict__ fb,
    float* __restrict__ sqn, float* __restrict__ pmax,
    float* __restrict__ nmin) {
  int wid = threadIdx.x >> 6, lane = threadIdx.x & 63;
  int row = blockIdx.x * 4 + wid;
  const float4* src = (const float4*)(f + (size_t)row * DD);
  float4 v0 = src[lane * 2];
  float4 v1 = src[lane * 2 + 1];
  float s = v0.x*v0.x + v0.y*v0.y + v0.z*v0.z + v0.w*v0.w
          + v1.x*v1.x + v1.y*v1.y + v1.z*v1.z + v1.w*v1.w;
  s16x8 o;
  o[0]=f2bf(v0.x); o[1]=f2bf(v0.y); o[2]=f2bf(v0.z); o[3]=f2bf(v0.w);
  o[4]=f2bf(v1.x); o[5]=f2bf(v1.y); o[6]=f2bf(v1.z); o[7]=f2bf(v1.w);
  *(s16x8*)&fb[(size_t)row * DD + lane * 8] = o;
  #pragma unroll
  for (int m = 1; m < 64; m <<= 1) s += __shfl_xor(s, m);
  if (lane == 0) {
    sqn[row] = s;
    pmax[row] = 0.f;
    nmin[row] = __int_as_float(0x7f800000);   // +inf
  }
}

// Upper-triangular 128x128 tiles of F*F^T via bf16 MFMA.
// R9 epilogue (verified 60.5 us) unchanged. Single change: K-loop is now
// double-buffered at BK=32 (2 x 16 KB staging, same 3 blocks/CU as R9):
// {vmcnt(0)+lgkmcnt(0) -> s_barrier -> STAGE(next) -> ds_read(cur)+MFMA}.
// Stage latency hides under the current step's compute instead of being
// exposed at a drain-after-issue barrier (R9 paid it 8x per tile).
// Swizzle (both-sides, rule 21): LDS[row][p] = G[row][p ^ s(row)],
// s(row) = (row&3) ^ ((row>>2)&3); read chunk = hi ^ s(row) -> 2-way max.
__global__ __launch_bounds__(256, 3) void tile_kernel(
    const short* __restrict__ fb, const float* __restrict__ sqn,
    const int* __restrict__ lab,
    float* __restrict__ pmax, float* __restrict__ nmin) {
  __shared__ __align__(16) short As[2][BM * BK2];   // 2 x 8 KB
  __shared__ __align__(16) short Bs[2][BM * BK2];   // 2 x 8 KB
  __shared__ float s_sq_r[BM], s_sq_c[BM];
  __shared__ int   s_lb_r[BM], s_lb_c[BM];
  __shared__ float colred[2][4][BM];                // 4 KB cross-wave col combine

  // XCD-aware swizzle (2080 % 8 == 0, bijective) then upper-tri decode
  int t0 = blockIdx.x;
  int t = (t0 & 7) * (NTILES / 8) + (t0 >> 3);
  int bi = (int)((129.0f - sqrtf(16641.0f - 8.0f * (float)t)) * 0.5f);
  if (bi < 0) bi = 0;
  while (bi > 0 && tri_off(bi) > t) --bi;
  while (tri_off(bi + 1) <= t) ++bi;
  int bj = bi + (t - tri_off(bi));
  int brow = bi * BM, bcol = bj * BM;

  int tid = threadIdx.x;
  int wid = tid >> 6, lane = tid & 63;
  int hi = lane >> 4, lo = lane & 15;

  if (tid < BM) {
    s_sq_r[tid] = sqn[brow + tid];
    s_lb_r[tid] = lab[brow + tid];
    s_sq_c[tid] = sqn[bcol + tid];
    s_lb_c[tid] = lab[bcol + tid];
  }

  f32x4 acc[2][8];
  #pragma unroll
  for (int a = 0; a < 2; ++a)
    #pragma unroll
    for (int b = 0; b < 8; ++b) acc[a][b] = (f32x4)(0.f);

  // staging: thread covers slots {tid, tid+256}; slot = row*4 + p
  // (row = slot>>2, p = slot&3, 16B chunks). Source chunk = p ^ s(row);
  // s(row) = (row&3)^((row>>2)&3) = ((tid>>2)&3)^((tid>>4)&3) for both slots.
  int srow  = tid >> 2;
  int schk  = (tid & 3) ^ ((tid >> 2) & 3) ^ ((tid >> 4) & 3);
  const short* gAs = fb + (size_t)(brow + srow) * DD + schk * 8;
  const short* gBs = fb + (size_t)(bcol + srow) * DD + schk * 8;

#define STAGE2(b, ktn) do {                                       \
    const short* ga_ = gAs + (ktn) * BK2;                         \
    const short* gb_ = gBs + (ktn) * BK2;                         \
    short* da_ = &As[b][tid * 8];                                 \
    short* db_ = &Bs[b][tid * 8];                                 \
    gload16(ga_, da_);                                            \
    gload16(ga_ + (size_t)64 * DD, da_ + 2048);                   \
    gload16(gb_, db_);                                            \
    gload16(gb_ + (size_t)64 * DD, db_ + 2048);                   \
  } while (0)

  // read-side: rows fc*16+lo (B) and wid*32+lo(+16) (A) all have
  // s(row) = (lo&3)^((lo>>2)&3); chunk = hi ^ s  (2-way banks, free)
  int sl  = (lo & 3) ^ ((lo >> 2) & 3);
  int csB = hi ^ sl;
  int aoff = (wid * 32 + lo) * BK2 + csB * 8;
  int boff0 = lo * BK2 + csB * 8;

  // prologue: stage K-step 0 into buf 0
  STAGE2(0, 0);

  #pragma unroll
  for (int kt = 0; kt < NKT2; ++kt) {
    int cur = kt & 1;
    asm volatile("s_waitcnt vmcnt(0) lgkmcnt(0)" ::: "memory");
    __builtin_amdgcn_s_barrier();
    __builtin_amdgcn_sched_barrier(0);
    if (kt + 1 < NKT2) STAGE2(cur ^ 1, kt + 1);
    const short* Ab = &As[cur][0];
    const short* Bb = &Bs[cur][0];
    s16x8 a0 = *(const s16x8*)(Ab + aoff);
    s16x8 a1 = *(const s16x8*)(Ab + aoff + 16 * BK2);
    s16x8 bfr[8];
    #pragma unroll
    for (int fc = 0; fc < 8; ++fc)
      bfr[fc] = *(const s16x8*)(Bb + boff0 + fc * 16 * BK2);
    #pragma unroll
    for (int fc = 0; fc < 8; ++fc) {
      acc[0][fc] = __builtin_amdgcn_mfma_f32_16x16x32_bf16(a0, bfr[fc], acc[0][fc], 0, 0, 0);
      acc[1][fc] = __builtin_amdgcn_mfma_f32_16x16x32_bf16(a1, bfr[fc], acc[1][fc], 0, 0, 0);
    }
  }
#undef STAGE2

  // Epilogue: SQUARED distances + masked max/min (identical to R9).
  const float FINF = __int_as_float(0x7f800000);
  float cvp[8], cvn[8];
  #pragma unroll
  for (int fc = 0; fc < 8; ++fc) { cvp[fc] = 0.f; cvn[fc] = FINF; }

  #pragma unroll
  for (int fr = 0; fr < 2; ++fr) {
    #pragma unroll
    for (int rg = 0; rg < 4; ++rg) {
      int rt = wid * 32 + fr * 16 + hi * 4 + rg;
      int gi = brow + rt;
      float sqi = s_sq_r[rt];
      int   li  = s_lb_r[rt];
      float vp = 0.f, vn = FINF;
      #pragma unroll
      for (int fc = 0; fc < 8; ++fc) {
        int ct = fc * 16 + lo;
        int gj = bcol + ct;
        float g = acc[fr][fc][rg];
        float v = fmaxf(sqi + s_sq_c[ct] - 2.0f * g, 0.f);   // squared dist
        if (gi == gj) v = 0.f;                               // zero the diagonal
        bool same = (li == s_lb_c[ct]);
        if (same) {
          vp = fmaxf(vp, v);
          cvp[fc] = fmaxf(cvp[fc], v);
        } else {
          vn = fminf(vn, v);
          cvn[fc] = fminf(cvn[fc], v);
        }
      }
      #pragma unroll
      for (int m = 1; m < 16; m <<= 1) {
        vp = fmaxf(vp, __shfl_xor(vp, m));
        vn = fminf(vn, __shfl_xor(vn, m));
      }
      if (lo == 0) {
        atomicMax((int*)&pmax[gi], __float_as_int(vp));
        atomicMin((int*)&nmin[gi], __float_as_int(vn));
      }
    }
  }
  // column-side: combine across hi groups in-wave, then cross-wave via LDS
  #pragma unroll
  for (int fc = 0; fc < 8; ++fc) {
    #pragma unroll
    for (int m = 16; m < 64; m <<= 1) {
      cvp[fc] = fmaxf(cvp[fc], __shfl_xor(cvp[fc], m));
      cvn[fc] = fminf(cvn[fc], __shfl_xor(cvn[fc], m));
    }
    if (hi == 0) {
      int ct = fc * 16 + lo;
      colred[0][wid][ct] = cvp[fc];
      colred[1][wid][ct] = cvn[fc];
    }
  }
  __syncthreads();
  if (tid < BM) {
    float p = colred[0][0][tid], n = colred[1][0][tid];
    #pragma unroll
    for (int w = 1; w < 4; ++w) {
      p = fmaxf(p, colred[0][w][tid]);
      n = fminf(n, colred[1][w][tid]);
    }
    int gj = bcol + tid;
    atomicMax((int*)&pmax[gj], __float_as_int(p));
    atomicMin((int*)&nmin[gj], __float_as_int(n));
  }
}

__global__ __launch_bounds__(256) void finalize_kernel(
    const float* __restrict__ pmax, const float* __restrict__ nmin,
    float* __restrict__ out) {
  int i = blockIdx.x * blockDim.x + threadIdx.x;
  if (i < NN) {
    const float FINF = __int_as_float(0x7f800000);
    float p = pmax[i];
    float n = nmin[i];
    // empty-negative fallback: axis_max == pmax when the whole row is same-label
    if (n == FINF) n = p;
    out[2 * i]     = sqrtf(p);
    out[2 * i + 1] = sqrtf(n);
  }
}

extern "C" void kernel_launch(void* const* d_in, const int* in_sizes, int n_in,
                              void* d_out, int out_size, void* d_ws, size_t ws_size,
                              hipStream_t stream) {
  const float* feat = (const float*)d_in[0];
  const int*   lab  = (const int*)d_in[1];
  float* out = (float*)d_out;

  char* ws = (char*)d_ws;
  short* fb   = (short*)ws;                                  // 8192*512*2 = 8388608 B
  float* sqn  = (float*)(ws + 8388608);                      // 32768 B
  float* pmax = (float*)(ws + 8388608 + 32768);              // 32768 B
  float* nmin = (float*)(ws + 8388608 + 2 * 32768);          // 32768 B

  prep_kernel<<<NN / 4, 256, 0, stream>>>(feat, fb, sqn, pmax, nmin);
  tile_kernel<<<NTILES, 256, 0, stream>>>(fb, sqn, lab, pmax, nmin);
  finalize_kernel<<<(NN + 255) / 256, 256, 0, stream>>>(pmax, nmin, out);
}

// Round 11
// 73.885 us; speedup vs baseline: 1.1007x; 1.1007x over previous
//
#include <hip/hip_runtime.h>
#include <stdint.h>

#define NN 8192
#define DD 512
#define BM 128
#define BK 64             // bf16 elements per K-step = 128 B rows in LDS
#define NKT (DD / BK)     // 8
#define NB 64             // NN / BM
#define NTILES 2080       // NB*(NB+1)/2 upper-triangular tiles

typedef short s16x8 __attribute__((ext_vector_type(8)));
typedef float f32x4 __attribute__((ext_vector_type(4)));

template <bool B> struct BoolC { static constexpr bool value = B; };

static __device__ __forceinline__ short f2bf(float x) {
  union { float f; uint32_t u; } c; c.f = x;
  uint32_t r = c.u + 0x7fffu + ((c.u >> 16) & 1u);   // RNE
  return (short)(r >> 16);
}

static __device__ __forceinline__ int tri_off(int b) {
  return b * NB - (b * (b - 1)) / 2;
}

static __device__ __forceinline__ void gload16(const void* g, void* l) {
  __builtin_amdgcn_global_load_lds(
      (const __attribute__((address_space(1))) void*)g,
      (__attribute__((address_space(3))) void*)l, 16, 0, 0);
}

// 4 waves/block, one row per wave: fp32 -> bf16, sq-norm, init reductions.
__global__ __launch_bounds__(256) void prep_kernel(
    const float* __restrict__ f, short* __restrict__ fb,
    float* __restrict__ sqn, float* __restrict__ pmax,
    float* __restrict__ nmin) {
  int wid = threadIdx.x >> 6, lane = threadIdx.x & 63;
  int row = blockIdx.x * 4 + wid;
  const float4* src = (const float4*)(f + (size_t)row * DD);
  float4 v0 = src[lane * 2];
  float4 v1 = src[lane * 2 + 1];
  float s = v0.x*v0.x + v0.y*v0.y + v0.z*v0.z + v0.w*v0.w
          + v1.x*v1.x + v1.y*v1.y + v1.z*v1.z + v1.w*v1.w;
  s16x8 o;
  o[0]=f2bf(v0.x); o[1]=f2bf(v0.y); o[2]=f2bf(v0.z); o[3]=f2bf(v0.w);
  o[4]=f2bf(v1.x); o[5]=f2bf(v1.y); o[6]=f2bf(v1.z); o[7]=f2bf(v1.w);
  *(s16x8*)&fb[(size_t)row * DD + lane * 8] = o;
  #pragma unroll
  for (int m = 1; m < 64; m <<= 1) s += __shfl_xor(s, m);
  if (lane == 0) {
    sqn[row] = s;
    pmax[row] = 0.f;
    nmin[row] = __int_as_float(0x7f800000);   // +inf
  }
}

// Upper-triangular 128x128 tiles of F*F^T via bf16 MFMA + global_load_lds.
// R9 base (60.5 us verified: swizzle 0-conflict, (256,3) no-spill, squared-
// space epilogue, no rmax). Two changes:
// 1) K-loop reorder: {sync -> ds_read frags -> MFMA ks0 -> read ks1 ->
//    sync -> STAGE(kt+1) -> MFMA ks1}. STAGE issues a full MFMA-half
//    before its drain (R9 drained immediately after issue, 8x/tile).
//    Same single buffer, same 2 __syncthreads()/iter, same LDS layout.
// 2) Epilogue templated on diag: off-diag blocks (2016/2080) drop the
//    per-element diagonal cmp+cndmask at compile time.
__global__ __launch_bounds__(256, 3) void tile_kernel(
    const short* __restrict__ fb, const float* __restrict__ sqn,
    const int* __restrict__ lab,
    float* __restrict__ pmax, float* __restrict__ nmin) {
  __shared__ __align__(16) short As[BM * 64];   // 16 KB, linear [row][64]
  __shared__ __align__(16) short Bs[BM * 64];   // 16 KB
  __shared__ float s_sq_r[BM], s_sq_c[BM];
  __shared__ int   s_lb_r[BM], s_lb_c[BM];
  __shared__ float colred[2][4][BM];            // 4 KB cross-wave col combine

  // XCD-aware swizzle (2080 % 8 == 0, bijective) then upper-tri decode
  int t0 = blockIdx.x;
  int t = (t0 & 7) * (NTILES / 8) + (t0 >> 3);
  int bi = (int)((129.0f - sqrtf(16641.0f - 8.0f * (float)t)) * 0.5f);
  if (bi < 0) bi = 0;
  while (bi > 0 && tri_off(bi) > t) --bi;
  while (tri_off(bi + 1) <= t) ++bi;
  int bj = bi + (t - tri_off(bi));
  int brow = bi * BM, bcol = bj * BM;
  bool diag_blk = (bi == bj);

  int tid = threadIdx.x;
  int wid = tid >> 6, lane = tid & 63;
  int hi = lane >> 4, lo = lane & 15;

  if (tid < BM) {
    s_sq_r[tid] = sqn[brow + tid];
    s_lb_r[tid] = lab[brow + tid];
    s_sq_c[tid] = sqn[bcol + tid];
    s_lb_c[tid] = lab[bcol + tid];
  }

  f32x4 acc[2][8];
  #pragma unroll
  for (int a = 0; a < 2; ++a)
    #pragma unroll
    for (int b = 0; b < 8; ++b) acc[a][b] = (f32x4)(0.f);

  // staging lane constants: lane covers row (seg*8 + lane>>3), 16B chunk
  // (lane&7), fetched from global chunk ((lane&7) ^ (row&7)) so that
  // LDS[row][p] = G[row][p ^ (row&7)]  (both-sides swizzle, linear dest)
  int lrow = lane >> 3;
  int lchunk = (lane & 7) ^ lrow;
  size_t lane_goff = (size_t)lrow * DD + lchunk * 8;   // shorts
  const short* gA = fb + (size_t)brow * DD + lane_goff;
  const short* gB = fb + (size_t)bcol * DD + lane_goff;

  // read-side swizzled chunk: want G[row][C], C = ks*4+hi; row&7 == lo&7
  int cs0 = hi ^ (lo & 7);          // ks=0
  int cs1 = cs0 ^ 4;                // ks=1
  int a0r = wid * 32 + lo;

#define STAGE(ktn) do {                                               \
    int kb_ = (ktn) * BK;                                             \
    _Pragma("unroll")                                                 \
    for (int i_ = 0; i_ < 4; ++i_) {                                  \
      int seg_ = wid * 4 + i_;                                        \
      gload16(gA + (size_t)seg_ * 8 * DD + kb_, &As[seg_ * 512]);     \
      gload16(gB + (size_t)seg_ * 8 * DD + kb_, &Bs[seg_ * 512]);     \
    }                                                                 \
  } while (0)

  STAGE(0);   // prologue

  for (int kt = 0; kt < NKT; ++kt) {
    __syncthreads();   // drains STAGE(kt) (vmcnt0) + prior reads done
    // ks=0 fragments + MFMA
    s16x8 a0 = *(const s16x8*)&As[a0r * 64 + cs0 * 8];
    s16x8 a1 = *(const s16x8*)&As[(a0r + 16) * 64 + cs0 * 8];
    s16x8 bfr[8];
    #pragma unroll
    for (int fc = 0; fc < 8; ++fc)
      bfr[fc] = *(const s16x8*)&Bs[(fc * 16 + lo) * 64 + cs0 * 8];
    #pragma unroll
    for (int fc = 0; fc < 8; ++fc) {
      acc[0][fc] = __builtin_amdgcn_mfma_f32_16x16x32_bf16(a0, bfr[fc], acc[0][fc], 0, 0, 0);
      acc[1][fc] = __builtin_amdgcn_mfma_f32_16x16x32_bf16(a1, bfr[fc], acc[1][fc], 0, 0, 0);
    }
    // ks=1 fragments
    s16x8 c0 = *(const s16x8*)&As[a0r * 64 + cs1 * 8];
    s16x8 c1 = *(const s16x8*)&As[(a0r + 16) * 64 + cs1 * 8];
    s16x8 dfr[8];
    #pragma unroll
    for (int fc = 0; fc < 8; ++fc)
      dfr[fc] = *(const s16x8*)&Bs[(fc * 16 + lo) * 64 + cs1 * 8];
    __syncthreads();   // all waves done reading (lgkm; vmcnt already 0)
    if (kt + 1 < NKT) STAGE(kt + 1);       // overwrite OK; drains next iter
    __builtin_amdgcn_sched_barrier(0);     // keep STAGE above the MFMA cluster
    #pragma unroll
    for (int fc = 0; fc < 8; ++fc) {
      acc[0][fc] = __builtin_amdgcn_mfma_f32_16x16x32_bf16(c0, dfr[fc], acc[0][fc], 0, 0, 0);
      acc[1][fc] = __builtin_amdgcn_mfma_f32_16x16x32_bf16(c1, dfr[fc], acc[1][fc], 0, 0, 0);
    }
  }
#undef STAGE

  // Epilogue: SQUARED distances + masked max/min, templated on diagonal.
  const float FINF = __int_as_float(0x7f800000);
  auto epilogue = [&](auto diag_c) {
    constexpr bool DIAG = decltype(diag_c)::value;
    float cvp[8], cvn[8];
    #pragma unroll
    for (int fc = 0; fc < 8; ++fc) { cvp[fc] = 0.f; cvn[fc] = FINF; }

    #pragma unroll
    for (int fr = 0; fr < 2; ++fr) {
      #pragma unroll
      for (int rg = 0; rg < 4; ++rg) {
        int rt = wid * 32 + fr * 16 + hi * 4 + rg;
        float sqi = s_sq_r[rt];
        int   li  = s_lb_r[rt];
        float vp = 0.f, vn = FINF;
        #pragma unroll
        for (int fc = 0; fc < 8; ++fc) {
          int ct = fc * 16 + lo;
          float g = acc[fr][fc][rg];
          float v = fmaxf(sqi + s_sq_c[ct] - 2.0f * g, 0.f);   // squared dist
          if constexpr (DIAG) { if (rt == ct) v = 0.f; }       // diagonal
          bool same = (li == s_lb_c[ct]);
          if (same) {
            vp = fmaxf(vp, v);
            cvp[fc] = fmaxf(cvp[fc], v);
          } else {
            vn = fminf(vn, v);
            cvn[fc] = fminf(cvn[fc], v);
          }
        }
        #pragma unroll
        for (int m = 1; m < 16; m <<= 1) {
          vp = fmaxf(vp, __shfl_xor(vp, m));
          vn = fminf(vn, __shfl_xor(vn, m));
        }
        if (lo == 0) {
          int gi = brow + rt;
          atomicMax((int*)&pmax[gi], __float_as_int(vp));
          atomicMin((int*)&nmin[gi], __float_as_int(vn));
        }
      }
    }
    // column-side: combine across hi groups in-wave, then cross-wave via LDS
    #pragma unroll
    for (int fc = 0; fc < 8; ++fc) {
      #pragma unroll
      for (int m = 16; m < 64; m <<= 1) {
        cvp[fc] = fmaxf(cvp[fc], __shfl_xor(cvp[fc], m));
        cvn[fc] = fminf(cvn[fc], __shfl_xor(cvn[fc], m));
      }
      if (hi == 0) {
        int ct = fc * 16 + lo;
        colred[0][wid][ct] = cvp[fc];
        colred[1][wid][ct] = cvn[fc];
      }
    }
    __syncthreads();
    if (tid < BM) {
      float p = colred[0][0][tid], n = colred[1][0][tid];
      #pragma unroll
      for (int w = 1; w < 4; ++w) {
        p = fmaxf(p, colred[0][w][tid]);
        n = fminf(n, colred[1][w][tid]);
      }
      int gj = bcol + tid;
      atomicMax((int*)&pmax[gj], __float_as_int(p));
      atomicMin((int*)&nmin[gj], __float_as_int(n));
    }
  };
  if (diag_blk) epilogue(BoolC<true>{});
  else          epilogue(BoolC<false>{});
}

__global__ __launch_bounds__(256) void finalize_kernel(
    const float* __restrict__ pmax, const float* __restrict__ nmin,
    float* __restrict__ out) {
  int i = blockIdx.x * blockDim.x + threadIdx.x;
  if (i < NN) {
    const float FINF = __int_as_float(0x7f800000);
    float p = pmax[i];
    float n = nmin[i];
    // empty-negative fallback: axis_max == pmax when the whole row is same-label
    if (n == FINF) n = p;
    out[2 * i]     = sqrtf(p);
    out[2 * i + 1] = sqrtf(n);
  }
}

extern "C" void kernel_launch(void* const* d_in, const int* in_sizes, int n_in,
                              void* d_out, int out_size, void* d_ws, size_t ws_size,
                              hipStream_t stream) {
  const float* feat = (const float*)d_in[0];
  const int*   lab  = (const int*)d_in[1];
  float* out = (float*)d_out;

  char* ws = (char*)d_ws;
  short* fb   = (short*)ws;                                  // 8192*512*2 = 8388608 B
  float* sqn  = (float*)(ws + 8388608);                      // 32768 B
  float* pmax = (float*)(ws + 8388608 + 32768);              // 32768 B
  float* nmin = (float*)(ws + 8388608 + 2 * 32768);          // 32768 B

  prep_kernel<<<NN / 4, 256, 0, stream>>>(feat, fb, sqn, pmax, nmin);
  tile_kernel<<<NTILES, 256, 0, stream>>>(fb, sqn, lab, pmax, nmin);
  finalize_kernel<<<(NN + 255) / 256, 256, 0, stream>>>(pmax, nmin, out);
}